// Round 1
// baseline (912.537 us; speedup 1.0000x reference)
//
#include <hip/hip_runtime.h>
#include <hip/hip_bf16.h>

#define NN 100000
#define NE 1600000
// IN=128, HID=256, OUT=128

typedef __attribute__((ext_vector_type(8))) short short8;
typedef __attribute__((ext_vector_type(4))) float float4v;

__device__ __forceinline__ unsigned short f2bf(float f) {
    unsigned int b = __float_as_uint(f);
    return (unsigned short)((b + 0x7fffu + ((b >> 16) & 1u)) >> 16);
}
__device__ __forceinline__ unsigned int pack_bf16(float lo, float hi) {
    return (unsigned int)f2bf(lo) | ((unsigned int)f2bf(hi) << 16);
}
__device__ __forceinline__ float bflo(unsigned int u) { return __uint_as_float(u << 16); }
__device__ __forceinline__ float bfhi(unsigned int u) { return __uint_as_float(u & 0xffff0000u); }

// ---- weight conversion: W1l/W1r -> bf16; wb2 = concat rows [W2l; W2r] ----
__global__ void k_wconv(const float* W1l, const float* W1r, const float* W2l, const float* W2r,
                        unsigned short* wb1l, unsigned short* wb1r, unsigned short* wb2) {
    int i = blockIdx.x * 256 + threadIdx.x;   // 0..32767 (each W is 32768 elems)
    wb1l[i] = f2bf(W1l[i]);
    wb1r[i] = f2bf(W1r[i]);
    wb2[i] = f2bf(W2l[i]);            // rows 0..127 of wb2 (k=256 contiguous)
    wb2[32768 + i] = f2bf(W2r[i]);    // rows 128..255
}

// ---- x -> packed bf16 pairs ----
__global__ void k_xconv(const float* x, unsigned int* xb) {
    int t = blockIdx.x * 256 + threadIdx.x;   // < NN*64
    float2 v = ((const float2*)x)[t];
    xb[t] = pack_bf16(v.x, v.y);
}

// ---- degree count ----
__global__ void k_deg(const int* ei, int* deg) {
    int e = blockIdx.x * 256 + threadIdx.x;
    if (e < NE) { atomicAdd(&deg[ei[NE + e]], 1); }
}

// ---- exclusive scan (3 phases) ----
__global__ void k_scan1(const int* deg, int* off, int* bsum) {
    __shared__ int s[256];
    int t = threadIdx.x, idx = blockIdx.x * 256 + t;
    int v = (idx < NN) ? deg[idx] : 0;
    s[t] = v;
    __syncthreads();
    for (int d = 1; d < 256; d <<= 1) {
        int val = (t >= d) ? s[t - d] : 0;
        __syncthreads();
        s[t] += val;
        __syncthreads();
    }
    if (idx < NN) off[idx] = s[t] - v;   // exclusive
    if (t == 255) bsum[blockIdx.x] = s[255];
}
__global__ void k_scan2(int* bsum, int nb) {
    if (threadIdx.x == 0 && blockIdx.x == 0) {
        int run = 0;
        for (int i = 0; i < nb; i++) { int t = bsum[i]; bsum[i] = run; run += t; }
    }
}
__global__ void k_scan3(int* off, const int* bsum, int* cursor) {
    int idx = blockIdx.x * 256 + threadIdx.x;
    if (idx < NN) {
        int o = off[idx] + bsum[blockIdx.x];
        off[idx] = o;
        cursor[idx] = o;
    }
}

// ---- CSR fill ----
__global__ void k_fill(const int* ei, int* cursor, int* csr) {
    int e = blockIdx.x * 256 + threadIdx.x;
    if (e < NE) {
        int r = ei[e], c = ei[NE + e];
        int p = atomicAdd(&cursor[c], 1);
        csr[p] = r;
    }
}

// ---- aggregation 1: ab1[n] = mean of xb over neighbors (wave per node) ----
__global__ void k_agg1(const unsigned int* xb, const int* off, const int* deg,
                       const int* csr, unsigned int* ab1) {
    int node = (blockIdx.x * 256 + threadIdx.x) >> 6;
    int lane = threadIdx.x & 63;
    if (node >= NN) return;
    int start = off[node], d = deg[node];
    float ax = 0.f, ay = 0.f;
    for (int j = 0; j < d; j++) {
        int nb = csr[start + j];
        unsigned int u = xb[nb * 64 + lane];
        ax += bflo(u); ay += bfhi(u);
    }
    float inv = 1.0f / (float)(d > 0 ? d : 1);
    ab1[node * 64 + lane] = pack_bf16(ax * inv, ay * inv);
}

// ---- GEMM1: h = relu(ab1 @ W1l^T + x @ W1r^T + b1), bf16 in, bf16 out ----
// wave computes 16 nodes x 256 cols, K=128, 16x16x32 mfma
__global__ void k_gemm1(const unsigned short* ab1, const unsigned short* xb,
                        const unsigned short* wb1l, const unsigned short* wb1r,
                        const float* b1, unsigned short* h) {
    int wave = (blockIdx.x * 256 + threadIdx.x) >> 6;
    if (wave >= NN / 16) return;
    int lane = threadIdx.x & 63;
    int mrow = lane & 15, quad = lane >> 4;
    int n0 = wave * 16;
    float4v acc[16];
#pragma unroll
    for (int i = 0; i < 16; i++) acc[i] = (float4v)(0.0f);
#pragma unroll
    for (int kk = 0; kk < 4; kk++) {
        int koff = kk * 32 + quad * 8;
        short8 a1 = *(const short8*)(ab1 + (n0 + mrow) * 128 + koff);
        short8 a2 = *(const short8*)(xb + (n0 + mrow) * 128 + koff);
#pragma unroll
        for (int ct = 0; ct < 16; ct++) {
            short8 bl = *(const short8*)(wb1l + (ct * 16 + mrow) * 128 + koff);
            acc[ct] = __builtin_amdgcn_mfma_f32_16x16x32_bf16(a1, bl, acc[ct], 0, 0, 0);
            short8 br = *(const short8*)(wb1r + (ct * 16 + mrow) * 128 + koff);
            acc[ct] = __builtin_amdgcn_mfma_f32_16x16x32_bf16(a2, br, acc[ct], 0, 0, 0);
        }
    }
#pragma unroll
    for (int ct = 0; ct < 16; ct++) {
        int col = ct * 16 + mrow;
        float bias = b1[col];
#pragma unroll
        for (int r = 0; r < 4; r++) {
            int node = n0 + quad * 4 + r;
            float v = acc[ct][r] + bias;
            v = v > 0.f ? v : 0.f;
            h[node * 256 + col] = f2bf(v);
        }
    }
}

// ---- GEMM2: cols 0..127 -> g = h @ W2l^T (bf16), cols 128..255 -> out = h @ W2r^T + b2 (f32) ----
__global__ void k_gemm2(const unsigned short* h, const unsigned short* wb2,
                        const float* b2, unsigned short* g, float* out) {
    int wave = (blockIdx.x * 256 + threadIdx.x) >> 6;
    if (wave >= NN / 16) return;
    int lane = threadIdx.x & 63;
    int mrow = lane & 15, quad = lane >> 4;
    int n0 = wave * 16;
    float4v acc[16];
#pragma unroll
    for (int i = 0; i < 16; i++) acc[i] = (float4v)(0.0f);
#pragma unroll
    for (int kk = 0; kk < 8; kk++) {
        int koff = kk * 32 + quad * 8;
        short8 a = *(const short8*)(h + (n0 + mrow) * 256 + koff);
#pragma unroll
        for (int ct = 0; ct < 16; ct++) {
            short8 b = *(const short8*)(wb2 + (ct * 16 + mrow) * 256 + koff);
            acc[ct] = __builtin_amdgcn_mfma_f32_16x16x32_bf16(a, b, acc[ct], 0, 0, 0);
        }
    }
#pragma unroll
    for (int ct = 0; ct < 16; ct++) {
        int col = ct * 16 + mrow;
#pragma unroll
        for (int r = 0; r < 4; r++) {
            int node = n0 + quad * 4 + r;
            float v = acc[ct][r];
            if (col < 128) {
                g[node * 128 + col] = f2bf(v);
            } else {
                out[node * 128 + (col - 128)] = v + b2[col - 128];
            }
        }
    }
}

// ---- aggregation 2: out[n] += mean of g over neighbors ----
__global__ void k_agg2(const unsigned int* g, const int* off, const int* deg,
                       const int* csr, float* out) {
    int node = (blockIdx.x * 256 + threadIdx.x) >> 6;
    int lane = threadIdx.x & 63;
    if (node >= NN) return;
    int start = off[node], d = deg[node];
    float ax = 0.f, ay = 0.f;
    for (int j = 0; j < d; j++) {
        int nb = csr[start + j];
        unsigned int u = g[nb * 64 + lane];
        ax += bflo(u); ay += bfhi(u);
    }
    float inv = 1.0f / (float)(d > 0 ? d : 1);
    float2* po = (float2*)(out + node * 128) + lane;
    float2 cur = *po;
    cur.x += ax * inv;
    cur.y += ay * inv;
    *po = cur;
}

extern "C" void kernel_launch(void* const* d_in, const int* in_sizes, int n_in,
                              void* d_out, int out_size, void* d_ws, size_t ws_size,
                              hipStream_t stream) {
    const float* x   = (const float*)d_in[0];
    const int*   ei  = (const int*)d_in[1];     // int32 (JAX default x64 disabled)
    const float* W1l = (const float*)d_in[2];
    const float* b1  = (const float*)d_in[3];
    const float* W1r = (const float*)d_in[4];
    const float* W2l = (const float*)d_in[5];
    const float* b2  = (const float*)d_in[6];
    const float* W2r = (const float*)d_in[7];
    float* out = (float*)d_out;

    char* p = (char*)d_ws;
    unsigned int* xb  = (unsigned int*)p;  p += (size_t)NN * 128 * 2;   // bf16 x
    unsigned int* ab1 = (unsigned int*)p;  p += (size_t)NN * 128 * 2;   // bf16 agg1
    unsigned short* h = (unsigned short*)p; p += (size_t)NN * 256 * 2;  // bf16 hidden
    unsigned int* g   = (unsigned int*)p;  p += (size_t)NN * 128 * 2;   // bf16 h@W2l^T
    unsigned short* wb1l = (unsigned short*)p; p += 32768 * 2;
    unsigned short* wb1r = (unsigned short*)p; p += 32768 * 2;
    unsigned short* wb2  = (unsigned short*)p; p += 65536 * 2;
    int* deg    = (int*)p; p += (size_t)NN * 4;
    int* off    = (int*)p; p += (size_t)(NN + 1024) * 4;
    int* cursor = (int*)p; p += (size_t)NN * 4;
    int* bsum   = (int*)p; p += 1024 * 4;
    int* csr    = (int*)p; p += (size_t)NE * 4;
    size_t needed = (size_t)(p - (char*)d_ws);
    if (ws_size < needed) return;  // workspace too small; fail loudly via absmax

    const int NB_SCAN = (NN + 255) / 256;  // 391

    hipMemsetAsync(deg, 0, (size_t)NN * 4, stream);
    k_wconv<<<128, 256, 0, stream>>>(W1l, W1r, W2l, W2r, wb1l, wb1r, wb2);
    k_xconv<<<NN * 64 / 256, 256, 0, stream>>>(x, xb);
    k_deg<<<(NE + 255) / 256, 256, 0, stream>>>(ei, deg);
    k_scan1<<<NB_SCAN, 256, 0, stream>>>(deg, off, bsum);
    k_scan2<<<1, 64, 0, stream>>>(bsum, NB_SCAN);
    k_scan3<<<NB_SCAN, 256, 0, stream>>>(off, bsum, cursor);
    k_fill<<<(NE + 255) / 256, 256, 0, stream>>>(ei, cursor, csr);
    k_agg1<<<NN / 4, 256, 0, stream>>>(xb, off, deg, csr, ab1);
    k_gemm1<<<(NN / 16 + 3) / 4, 256, 0, stream>>>((const unsigned short*)ab1, (const unsigned short*)xb,
                                                   wb1l, wb1r, b1, h);
    k_gemm2<<<(NN / 16 + 3) / 4, 256, 0, stream>>>(h, wb2, b2, (unsigned short*)g, out);
    k_agg2<<<NN / 4, 256, 0, stream>>>(g, off, deg, csr, out);
}

// Round 2
// 491.406 us; speedup vs baseline: 1.8570x; 1.8570x over previous
//
#include <hip/hip_runtime.h>
#include <hip/hip_bf16.h>

#define NN 100000
#define NE 1600000
#define NCHUNK ((NN + 127) / 128)   // 782
#define NB_SCAN ((NN + 255) / 256)  // 391

typedef __attribute__((ext_vector_type(8))) short short8;
typedef __attribute__((ext_vector_type(4))) float float4v;

__device__ __forceinline__ unsigned short f2bf(float f) {
    unsigned int b = __float_as_uint(f);
    return (unsigned short)((b + 0x7fffu + ((b >> 16) & 1u)) >> 16);
}
__device__ __forceinline__ unsigned int pack_bf16(float lo, float hi) {
    return (unsigned int)f2bf(lo) | ((unsigned int)f2bf(hi) << 16);
}
__device__ __forceinline__ float bflo(unsigned int u) { return __uint_as_float(u << 16); }
__device__ __forceinline__ float bfhi(unsigned int u) { return __uint_as_float(u & 0xffff0000u); }

__device__ __forceinline__ void addp(float* a, uint4 u) {
    a[0] += bflo(u.x); a[1] += bfhi(u.x);
    a[2] += bflo(u.y); a[3] += bfhi(u.y);
    a[4] += bflo(u.z); a[5] += bfhi(u.z);
    a[6] += bflo(u.w); a[7] += bfhi(u.w);
}

// ---- weights: wb1[ct][0:128]=W1l[ct], [128:256]=W1r[ct]; wb2=[W2l;W2r] rows ----
__global__ void k_wconv(const float* W1l, const float* W1r, const float* W2l, const float* W2r,
                        unsigned short* wb1, unsigned short* wb2) {
    int i = blockIdx.x * 256 + threadIdx.x;   // < 32768
    int r1 = i >> 7, c1 = i & 127;            // W1l/W1r are 256x128
    wb1[r1 * 256 + c1]       = f2bf(W1l[i]);
    wb1[r1 * 256 + 128 + c1] = f2bf(W1r[i]);
    wb2[i]         = f2bf(W2l[i]);            // 128x256, k contiguous
    wb2[32768 + i] = f2bf(W2r[i]);
}

// ---- x -> bf16-packed into axb cols 128..255 (uints 64..127 of each 128-uint row) ----
__global__ void k_xconv(const float* x, unsigned int* axb_u) {
    int t = blockIdx.x * 256 + threadIdx.x;   // < NN*64
    int node = t >> 6, i = t & 63;
    float2 v = ((const float2*)x)[t];
    axb_u[(size_t)node * 128 + 64 + i] = pack_bf16(v.x, v.y);
}

// ---- degree count ----
__global__ void k_deg(const int* ei, int* deg) {
    int e = blockIdx.x * 256 + threadIdx.x;
    if (e < NE) atomicAdd(&deg[ei[NE + e]], 1);
}

// ---- exclusive scan ----
__global__ void k_scan1(const int* deg, int* off, int* bsum) {
    __shared__ int s[256];
    int t = threadIdx.x, idx = blockIdx.x * 256 + t;
    int v = (idx < NN) ? deg[idx] : 0;
    s[t] = v;
    __syncthreads();
    for (int d = 1; d < 256; d <<= 1) {
        int val = (t >= d) ? s[t - d] : 0;
        __syncthreads();
        s[t] += val;
        __syncthreads();
    }
    if (idx < NN) off[idx] = s[t] - v;
    if (t == 255) bsum[blockIdx.x] = s[255];
}
__global__ void k_scan2(int* bsum, int nb) {
    __shared__ int s[512];
    int t = threadIdx.x;
    int v = (t < nb) ? bsum[t] : 0;
    s[t] = v;
    __syncthreads();
    for (int d = 1; d < 512; d <<= 1) {
        int val = (t >= d) ? s[t - d] : 0;
        __syncthreads();
        s[t] += val;
        __syncthreads();
    }
    if (t < nb) bsum[t] = s[t] - v;   // exclusive
}
__global__ void k_scan3(int* off, const int* bsum, int* cursor) {
    int idx = blockIdx.x * 256 + threadIdx.x;
    if (idx < NN) {
        int o = off[idx] + bsum[blockIdx.x];
        off[idx] = o;
        cursor[idx] = o;
    }
}

// ---- CSR fill ----
__global__ void k_fill(const int* ei, int* cursor, int* csr) {
    int e = blockIdx.x * 256 + threadIdx.x;
    if (e < NE) {
        int r = ei[e], c = ei[NE + e];
        int p = atomicAdd(&cursor[c], 1);
        csr[p] = r;
    }
}

// ---- agg1: mean of x-part of axb over neighbors -> axb cols 0..127 ----
// wave per node; 4 subwaves handle 4 neighbors concurrently; 16B/lane gathers
__global__ void k_agg1(const unsigned int* axb_u, const int* off, const int* deg,
                       const int* csr, unsigned int* axb_w) {
    int wid = (blockIdx.x * 256 + threadIdx.x) >> 6;
    if (wid >= NN) return;
    int lane = threadIdx.x & 63;
    int sub = lane >> 4, l16 = lane & 15;
    int start = off[wid], d = deg[wid];
    float a[8] = {0.f, 0.f, 0.f, 0.f, 0.f, 0.f, 0.f, 0.f};
    int j = sub;
    for (; j + 4 < d; j += 8) {
        int nb0 = csr[start + j];
        int nb1 = csr[start + j + 4];
        uint4 u0 = *(const uint4*)(axb_u + (size_t)nb0 * 128 + 64 + (l16 << 2));
        uint4 u1 = *(const uint4*)(axb_u + (size_t)nb1 * 128 + 64 + (l16 << 2));
        addp(a, u0); addp(a, u1);
    }
    if (j < d) {
        int nb = csr[start + j];
        uint4 u = *(const uint4*)(axb_u + (size_t)nb * 128 + 64 + (l16 << 2));
        addp(a, u);
    }
#pragma unroll
    for (int i = 0; i < 8; i++) {
        a[i] += __shfl_xor(a[i], 16, 64);
        a[i] += __shfl_xor(a[i], 32, 64);
    }
    if (sub == 0) {
        float inv = 1.0f / (float)(d > 0 ? d : 1);
        uint4 o;
        o.x = pack_bf16(a[0] * inv, a[1] * inv);
        o.y = pack_bf16(a[2] * inv, a[3] * inv);
        o.z = pack_bf16(a[4] * inv, a[5] * inv);
        o.w = pack_bf16(a[6] * inv, a[7] * inv);
        *(uint4*)(axb_w + (size_t)wid * 128 + (l16 << 2)) = o;
    }
}

// ---- agg2: out += mean of g over neighbors ----
__global__ void k_agg2(const unsigned int* g, const int* off, const int* deg,
                       const int* csr, float* out) {
    int wid = (blockIdx.x * 256 + threadIdx.x) >> 6;
    if (wid >= NN) return;
    int lane = threadIdx.x & 63;
    int sub = lane >> 4, l16 = lane & 15;
    int start = off[wid], d = deg[wid];
    float a[8] = {0.f, 0.f, 0.f, 0.f, 0.f, 0.f, 0.f, 0.f};
    int j = sub;
    for (; j + 4 < d; j += 8) {
        int nb0 = csr[start + j];
        int nb1 = csr[start + j + 4];
        uint4 u0 = *(const uint4*)(g + (size_t)nb0 * 64 + (l16 << 2));
        uint4 u1 = *(const uint4*)(g + (size_t)nb1 * 64 + (l16 << 2));
        addp(a, u0); addp(a, u1);
    }
    if (j < d) {
        int nb = csr[start + j];
        uint4 u = *(const uint4*)(g + (size_t)nb * 64 + (l16 << 2));
        addp(a, u);
    }
#pragma unroll
    for (int i = 0; i < 8; i++) {
        a[i] += __shfl_xor(a[i], 16, 64);
        a[i] += __shfl_xor(a[i], 32, 64);
    }
    if (sub == 0) {
        float inv = 1.0f / (float)(d > 0 ? d : 1);
        float4* po = (float4*)(out + (size_t)wid * 128) + (l16 << 1);
        float4 c0 = po[0], c1 = po[1];
        c0.x += a[0] * inv; c0.y += a[1] * inv; c0.z += a[2] * inv; c0.w += a[3] * inv;
        c1.x += a[4] * inv; c1.y += a[5] * inv; c1.z += a[6] * inv; c1.w += a[7] * inv;
        po[0] = c0; po[1] = c1;
    }
}

// ---- persistent GEMM: M=100000, N=256, K=256; full B (128KB) staged in LDS once ----
// wave: M=32 (2 row-blocks) x N=256 (16 ct tiles); block: 4 waves = 128 rows/chunk
__global__ __launch_bounds__(256, 1) void k_gemm1(const unsigned short* A, const unsigned short* wb,
                                                  const float* b1, unsigned short* H) {
    __shared__ unsigned short Bs[256 * 256];   // 128 KB
    int t = threadIdx.x;
    {
        const short8* src = (const short8*)wb;
        short8* dst = (short8*)Bs;
#pragma unroll
        for (int i = 0; i < 32; i++) dst[i * 256 + t] = src[i * 256 + t];
    }
    __syncthreads();
    int wv = t >> 6, lane = t & 63;
    int mrow = lane & 15, quad = lane >> 4;
    float bias[16];
#pragma unroll
    for (int ct = 0; ct < 16; ct++) bias[ct] = b1[ct * 16 + mrow];
    for (int chunk = blockIdx.x; chunk < NCHUNK; chunk += gridDim.x) {
        int base = chunk * 128 + wv * 32;
        if (base >= NN) continue;
        short8 afr[2][8];
#pragma unroll
        for (int kk = 0; kk < 8; kk++) {
            afr[0][kk] = *(const short8*)(A + (size_t)(base + mrow) * 256 + kk * 32 + quad * 8);
            afr[1][kk] = *(const short8*)(A + (size_t)(base + 16 + mrow) * 256 + kk * 32 + quad * 8);
        }
        float4v acc[2][16];
#pragma unroll
        for (int h = 0; h < 2; h++)
#pragma unroll
            for (int ct = 0; ct < 16; ct++) acc[h][ct] = (float4v)(0.0f);
#pragma unroll
        for (int kk = 0; kk < 8; kk++) {
            int koff = kk * 32 + quad * 8;
#pragma unroll
            for (int ct = 0; ct < 16; ct++) {
                short8 b = *(const short8*)(Bs + (ct * 16 + mrow) * 256 + koff);
                acc[0][ct] = __builtin_amdgcn_mfma_f32_16x16x32_bf16(afr[0][kk], b, acc[0][ct], 0, 0, 0);
                acc[1][ct] = __builtin_amdgcn_mfma_f32_16x16x32_bf16(afr[1][kk], b, acc[1][ct], 0, 0, 0);
            }
        }
#pragma unroll
        for (int ct = 0; ct < 16; ct++) {
            int col = ct * 16 + mrow;
#pragma unroll
            for (int h = 0; h < 2; h++) {
#pragma unroll
                for (int r = 0; r < 4; r++) {
                    int node = base + h * 16 + quad * 4 + r;
                    float v = acc[h][ct][r] + bias[ct];
                    v = fmaxf(v, 0.f);
                    H[(size_t)node * 256 + col] = f2bf(v);
                }
            }
        }
    }
}

__global__ __launch_bounds__(256, 1) void k_gemm2(const unsigned short* A, const unsigned short* wb,
                                                  const float* b2, unsigned short* g, float* out) {
    __shared__ unsigned short Bs[256 * 256];   // 128 KB
    int t = threadIdx.x;
    {
        const short8* src = (const short8*)wb;
        short8* dst = (short8*)Bs;
#pragma unroll
        for (int i = 0; i < 32; i++) dst[i * 256 + t] = src[i * 256 + t];
    }
    __syncthreads();
    int wv = t >> 6, lane = t & 63;
    int mrow = lane & 15, quad = lane >> 4;
    float bias[8];
#pragma unroll
    for (int i = 0; i < 8; i++) bias[i] = b2[i * 16 + mrow];
    for (int chunk = blockIdx.x; chunk < NCHUNK; chunk += gridDim.x) {
        int base = chunk * 128 + wv * 32;
        if (base >= NN) continue;
        short8 afr[2][8];
#pragma unroll
        for (int kk = 0; kk < 8; kk++) {
            afr[0][kk] = *(const short8*)(A + (size_t)(base + mrow) * 256 + kk * 32 + quad * 8);
            afr[1][kk] = *(const short8*)(A + (size_t)(base + 16 + mrow) * 256 + kk * 32 + quad * 8);
        }
        float4v acc[2][16];
#pragma unroll
        for (int h = 0; h < 2; h++)
#pragma unroll
            for (int ct = 0; ct < 16; ct++) acc[h][ct] = (float4v)(0.0f);
#pragma unroll
        for (int kk = 0; kk < 8; kk++) {
            int koff = kk * 32 + quad * 8;
#pragma unroll
            for (int ct = 0; ct < 16; ct++) {
                short8 b = *(const short8*)(Bs + (ct * 16 + mrow) * 256 + koff);
                acc[0][ct] = __builtin_amdgcn_mfma_f32_16x16x32_bf16(afr[0][kk], b, acc[0][ct], 0, 0, 0);
                acc[1][ct] = __builtin_amdgcn_mfma_f32_16x16x32_bf16(afr[1][kk], b, acc[1][ct], 0, 0, 0);
            }
        }
#pragma unroll
        for (int ct = 0; ct < 16; ct++) {
            int col = ct * 16 + mrow;
#pragma unroll
            for (int h = 0; h < 2; h++) {
#pragma unroll
                for (int r = 0; r < 4; r++) {
                    int node = base + h * 16 + quad * 4 + r;
                    float v = acc[h][ct][r];
                    if (ct < 8) {
                        g[(size_t)node * 128 + col] = f2bf(v);
                    } else {
                        out[(size_t)node * 128 + (col - 128)] = v + bias[ct - 8];
                    }
                }
            }
        }
    }
}

extern "C" void kernel_launch(void* const* d_in, const int* in_sizes, int n_in,
                              void* d_out, int out_size, void* d_ws, size_t ws_size,
                              hipStream_t stream) {
    const float* x   = (const float*)d_in[0];
    const int*   ei  = (const int*)d_in[1];
    const float* W1l = (const float*)d_in[2];
    const float* b1  = (const float*)d_in[3];
    const float* W1r = (const float*)d_in[4];
    const float* W2l = (const float*)d_in[5];
    const float* b2  = (const float*)d_in[6];
    const float* W2r = (const float*)d_in[7];
    float* out = (float*)d_out;

    char* p = (char*)d_ws;
    unsigned int* axb = (unsigned int*)p; p += (size_t)NN * 256 * 2;  // [agg(128) | x(128)] bf16
    unsigned short* h = (unsigned short*)p; p += (size_t)NN * 256 * 2;
    unsigned int* g   = (unsigned int*)p;  p += (size_t)NN * 128 * 2;
    unsigned short* wb1 = (unsigned short*)p; p += 65536 * 2;
    unsigned short* wb2 = (unsigned short*)p; p += 65536 * 2;
    int* deg    = (int*)p; p += (size_t)NN * 4;
    int* off    = (int*)p; p += (size_t)NN * 4;
    int* cursor = (int*)p; p += (size_t)NN * 4;
    int* bsum   = (int*)p; p += 512 * 4;
    int* csr    = (int*)p; p += (size_t)NE * 4;
    if (ws_size < (size_t)(p - (char*)d_ws)) return;

    hipMemsetAsync(deg, 0, (size_t)NN * 4, stream);
    k_wconv<<<128, 256, 0, stream>>>(W1l, W1r, W2l, W2r, wb1, wb2);
    k_xconv<<<NN * 64 / 256, 256, 0, stream>>>(x, axb);
    k_deg<<<(NE + 255) / 256, 256, 0, stream>>>(ei, deg);
    k_scan1<<<NB_SCAN, 256, 0, stream>>>(deg, off, bsum);
    k_scan2<<<1, 512, 0, stream>>>(bsum, NB_SCAN);
    k_scan3<<<NB_SCAN, 256, 0, stream>>>(off, bsum, cursor);
    k_fill<<<(NE + 255) / 256, 256, 0, stream>>>(ei, cursor, csr);
    k_agg1<<<NN * 64 / 256, 256, 0, stream>>>(axb, off, deg, csr, axb);
    k_gemm1<<<256, 256, 0, stream>>>((const unsigned short*)axb, wb1, b1, h);
    k_gemm2<<<256, 256, 0, stream>>>(h, wb2, b2, (unsigned short*)g, out);
    k_agg2<<<25000, 256, 0, stream>>>(g, off, deg, csr, out);
}

// Round 3
// 396.532 us; speedup vs baseline: 2.3013x; 1.2393x over previous
//
#include <hip/hip_runtime.h>
#include <hip/hip_bf16.h>

#define NN 100000
#define NE 1600000
#define NCHUNK ((NN + 127) / 128)   // 782 (gemm row chunks)
#define NPB 512                      // nodes per bucket (pow2, shift 9)
#define NB 256                       // bucket slots (196 active)
#define CHUNK 8192                   // edges per bscatter block
#define NCH ((NE + CHUNK - 1) / CHUNK)  // 196

typedef __attribute__((ext_vector_type(8))) short short8;
typedef __attribute__((ext_vector_type(4))) float float4v;

__device__ __forceinline__ unsigned short f2bf(float f) {
    unsigned int b = __float_as_uint(f);
    return (unsigned short)((b + 0x7fffu + ((b >> 16) & 1u)) >> 16);
}
__device__ __forceinline__ unsigned int pack_bf16(float lo, float hi) {
    return (unsigned int)f2bf(lo) | ((unsigned int)f2bf(hi) << 16);
}
__device__ __forceinline__ float bflo(unsigned int u) { return __uint_as_float(u << 16); }
__device__ __forceinline__ float bfhi(unsigned int u) { return __uint_as_float(u & 0xffff0000u); }

__device__ __forceinline__ void addp(float* a, uint4 u) {
    a[0] += bflo(u.x); a[1] += bfhi(u.x);
    a[2] += bflo(u.y); a[3] += bfhi(u.y);
    a[4] += bflo(u.z); a[5] += bfhi(u.z);
    a[6] += bflo(u.w); a[7] += bfhi(u.w);
}

// ---- weights: wb1[ct][0:128]=W1l[ct], [128:256]=W1r[ct]; wb2=[W2l;W2r] rows ----
__global__ void k_wconv(const float* W1l, const float* W1r, const float* W2l, const float* W2r,
                        unsigned short* wb1, unsigned short* wb2) {
    int i = blockIdx.x * 256 + threadIdx.x;   // < 32768
    int r1 = i >> 7, c1 = i & 127;            // W1l/W1r are 256x128
    wb1[r1 * 256 + c1]       = f2bf(W1l[i]);
    wb1[r1 * 256 + 128 + c1] = f2bf(W1r[i]);
    wb2[i]         = f2bf(W2l[i]);            // 128x256, k contiguous
    wb2[32768 + i] = f2bf(W2r[i]);
}

// ---- x -> bf16-packed into axb cols 128..255 ----
__global__ void k_xconv(const float* x, unsigned int* axb_u) {
    int t = blockIdx.x * 256 + threadIdx.x;   // < NN*64
    int node = t >> 6, i = t & 63;
    float2 v = ((const float2*)x)[t];
    axb_u[(size_t)node * 128 + 64 + i] = pack_bf16(v.x, v.y);
}

// ---- CSR pipeline (bucket counting sort) ----
__global__ void k_bcount(const int* ei, int* bcnt) {
    __shared__ int h[NB];
    int t = threadIdx.x;
    h[t] = 0;
    __syncthreads();
    for (int e = blockIdx.x * 256 + t; e < NE; e += gridDim.x * 256)
        atomicAdd(&h[ei[NE + e] >> 9], 1);
    __syncthreads();
    if (h[t]) atomicAdd(&bcnt[t], h[t]);
}

__global__ void k_bscan(const int* bcnt, int* boff, int* bcur) {
    __shared__ int s[NB];
    int t = threadIdx.x;
    int v = bcnt[t];
    s[t] = v;
    __syncthreads();
    for (int d = 1; d < NB; d <<= 1) {
        int val = (t >= d) ? s[t - d] : 0;
        __syncthreads();
        s[t] += val;
        __syncthreads();
    }
    boff[t + 1] = s[t];
    if (t == 0) boff[0] = 0;
    bcur[t] = s[t] - v;   // exclusive
}

__global__ __launch_bounds__(256) void k_bscatter(const int* ei, int* bcur, uint2* pairs) {
    __shared__ uint2 buf[CHUNK];       // 64 KB
    __shared__ int cnt[NB];
    __shared__ int lbase[NB];
    __shared__ int lcur[NB];
    __shared__ int gpos[NB];
    int t = threadIdx.x;
    int e0 = blockIdx.x * CHUNK;
    int nedge = NE - e0; if (nedge > CHUNK) nedge = CHUNK;
    cnt[t] = 0;
    __syncthreads();
    for (int i = t; i < nedge; i += 256)
        atomicAdd(&cnt[ei[NE + e0 + i] >> 9], 1);
    __syncthreads();
    int v = cnt[t];
    lcur[t] = v;
    __syncthreads();
    for (int d = 1; d < NB; d <<= 1) {
        int val = (t >= d) ? lcur[t - d] : 0;
        __syncthreads();
        lcur[t] += val;
        __syncthreads();
    }
    lbase[t] = lcur[t] - v;
    gpos[t] = atomicAdd(&bcur[t], v);
    __syncthreads();
    lcur[t] = lbase[t];
    __syncthreads();
    for (int i = t; i < nedge; i += 256) {
        int r = ei[e0 + i], c = ei[NE + e0 + i];
        int b = c >> 9;
        int p = atomicAdd(&lcur[b], 1);
        buf[p] = make_uint2((unsigned)r, (unsigned)c);
    }
    __syncthreads();
    // flush bucket t as a contiguous burst
    int n = cnt[t], lb = lbase[t], gp = gpos[t];
    for (int i = 0; i < n; i++)
        pairs[gp + i] = buf[lb + i];
}

__global__ __launch_bounds__(256) void k_build(const uint2* pairs, const int* boff,
                                               int* off, int* deg, int* csr) {
    __shared__ int ldeg[NPB];
    __shared__ int lcur[NPB];
    __shared__ int sscan[256];
    int b = blockIdx.x;
    int nbase = b * NPB;
    if (nbase >= NN) return;
    int t = threadIdx.x;
    int base = boff[b], cntb = boff[b + 1] - base;
    ldeg[t] = 0; ldeg[t + 256] = 0;
    __syncthreads();
    for (int i = t; i < cntb; i += 256) {
        uint2 pr = pairs[base + i];
        atomicAdd(&ldeg[pr.y - nbase], 1);
    }
    __syncthreads();
    int d0 = ldeg[2 * t], d1 = ldeg[2 * t + 1];
    int v = d0 + d1;
    sscan[t] = v;
    __syncthreads();
    for (int d = 1; d < 256; d <<= 1) {
        int val = (t >= d) ? sscan[t - d] : 0;
        __syncthreads();
        sscan[t] += val;
        __syncthreads();
    }
    int ex = sscan[t] - v;
    lcur[2 * t] = ex; lcur[2 * t + 1] = ex + d0;
    __syncthreads();
    int nloc = NN - nbase; if (nloc > NPB) nloc = NPB;
    for (int ln = t; ln < nloc; ln += 256) {
        off[nbase + ln] = base + lcur[ln];
        deg[nbase + ln] = ldeg[ln];
    }
    __syncthreads();
    for (int i = t; i < cntb; i += 256) {
        uint2 pr = pairs[base + i];
        int p = atomicAdd(&lcur[pr.y - nbase], 1);
        csr[base + p] = (int)pr.x;   // scatter within L2-resident 32 KB window
    }
}

// ---- agg1: mean of x-part of axb over neighbors -> axb cols 0..127 ----
__global__ void k_agg1(const unsigned int* axb_u, const int* off, const int* deg,
                       const int* csr, unsigned int* axb_w) {
    int wid = (blockIdx.x * 256 + threadIdx.x) >> 6;
    if (wid >= NN) return;
    int lane = threadIdx.x & 63;
    int sub = lane >> 4, l16 = lane & 15;
    int start = off[wid], d = deg[wid];
    float a[8] = {0.f, 0.f, 0.f, 0.f, 0.f, 0.f, 0.f, 0.f};
    int j = sub;
    for (; j + 4 < d; j += 8) {
        int nb0 = csr[start + j];
        int nb1 = csr[start + j + 4];
        uint4 u0 = *(const uint4*)(axb_u + (size_t)nb0 * 128 + 64 + (l16 << 2));
        uint4 u1 = *(const uint4*)(axb_u + (size_t)nb1 * 128 + 64 + (l16 << 2));
        addp(a, u0); addp(a, u1);
    }
    if (j < d) {
        int nb = csr[start + j];
        uint4 u = *(const uint4*)(axb_u + (size_t)nb * 128 + 64 + (l16 << 2));
        addp(a, u);
    }
#pragma unroll
    for (int i = 0; i < 8; i++) {
        a[i] += __shfl_xor(a[i], 16, 64);
        a[i] += __shfl_xor(a[i], 32, 64);
    }
    if (sub == 0) {
        float inv = 1.0f / (float)(d > 0 ? d : 1);
        uint4 o;
        o.x = pack_bf16(a[0] * inv, a[1] * inv);
        o.y = pack_bf16(a[2] * inv, a[3] * inv);
        o.z = pack_bf16(a[4] * inv, a[5] * inv);
        o.w = pack_bf16(a[6] * inv, a[7] * inv);
        *(uint4*)(axb_w + (size_t)wid * 128 + (l16 << 2)) = o;
    }
}

// ---- agg2: out += mean of g over neighbors ----
__global__ void k_agg2(const unsigned int* g, const int* off, const int* deg,
                       const int* csr, float* out) {
    int wid = (blockIdx.x * 256 + threadIdx.x) >> 6;
    if (wid >= NN) return;
    int lane = threadIdx.x & 63;
    int sub = lane >> 4, l16 = lane & 15;
    int start = off[wid], d = deg[wid];
    float a[8] = {0.f, 0.f, 0.f, 0.f, 0.f, 0.f, 0.f, 0.f};
    int j = sub;
    for (; j + 4 < d; j += 8) {
        int nb0 = csr[start + j];
        int nb1 = csr[start + j + 4];
        uint4 u0 = *(const uint4*)(g + (size_t)nb0 * 64 + (l16 << 2));
        uint4 u1 = *(const uint4*)(g + (size_t)nb1 * 64 + (l16 << 2));
        addp(a, u0); addp(a, u1);
    }
    if (j < d) {
        int nb = csr[start + j];
        uint4 u = *(const uint4*)(g + (size_t)nb * 64 + (l16 << 2));
        addp(a, u);
    }
#pragma unroll
    for (int i = 0; i < 8; i++) {
        a[i] += __shfl_xor(a[i], 16, 64);
        a[i] += __shfl_xor(a[i], 32, 64);
    }
    if (sub == 0) {
        float inv = 1.0f / (float)(d > 0 ? d : 1);
        float4* po = (float4*)(out + (size_t)wid * 128) + (l16 << 1);
        float4 c0 = po[0], c1 = po[1];
        c0.x += a[0] * inv; c0.y += a[1] * inv; c0.z += a[2] * inv; c0.w += a[3] * inv;
        c1.x += a[4] * inv; c1.y += a[5] * inv; c1.z += a[6] * inv; c1.w += a[7] * inv;
        po[0] = c0; po[1] = c1;
    }
}

// ---- persistent GEMM: M=100000, N=256, K=256; full B (128KB) staged in LDS once ----
__global__ __launch_bounds__(256, 1) void k_gemm1(const unsigned short* A, const unsigned short* wb,
                                                  const float* b1, unsigned short* H) {
    __shared__ unsigned short Bs[256 * 256];   // 128 KB
    int t = threadIdx.x;
    {
        const short8* src = (const short8*)wb;
        short8* dst = (short8*)Bs;
#pragma unroll
        for (int i = 0; i < 32; i++) dst[i * 256 + t] = src[i * 256 + t];
    }
    __syncthreads();
    int wv = t >> 6, lane = t & 63;
    int mrow = lane & 15, quad = lane >> 4;
    float bias[16];
#pragma unroll
    for (int ct = 0; ct < 16; ct++) bias[ct] = b1[ct * 16 + mrow];
    for (int chunk = blockIdx.x; chunk < NCHUNK; chunk += gridDim.x) {
        int base = chunk * 128 + wv * 32;
        if (base >= NN) continue;
        short8 afr[2][8];
#pragma unroll
        for (int kk = 0; kk < 8; kk++) {
            afr[0][kk] = *(const short8*)(A + (size_t)(base + mrow) * 256 + kk * 32 + quad * 8);
            afr[1][kk] = *(const short8*)(A + (size_t)(base + 16 + mrow) * 256 + kk * 32 + quad * 8);
        }
        float4v acc[2][16];
#pragma unroll
        for (int h = 0; h < 2; h++)
#pragma unroll
            for (int ct = 0; ct < 16; ct++) acc[h][ct] = (float4v)(0.0f);
#pragma unroll
        for (int kk = 0; kk < 8; kk++) {
            int koff = kk * 32 + quad * 8;
#pragma unroll
            for (int ct = 0; ct < 16; ct++) {
                short8 b = *(const short8*)(Bs + (ct * 16 + mrow) * 256 + koff);
                acc[0][ct] = __builtin_amdgcn_mfma_f32_16x16x32_bf16(afr[0][kk], b, acc[0][ct], 0, 0, 0);
                acc[1][ct] = __builtin_amdgcn_mfma_f32_16x16x32_bf16(afr[1][kk], b, acc[1][ct], 0, 0, 0);
            }
        }
#pragma unroll
        for (int ct = 0; ct < 16; ct++) {
            int col = ct * 16 + mrow;
#pragma unroll
            for (int h = 0; h < 2; h++) {
#pragma unroll
                for (int r = 0; r < 4; r++) {
                    int node = base + h * 16 + quad * 4 + r;
                    float v = acc[h][ct][r] + bias[ct];
                    v = fmaxf(v, 0.f);
                    H[(size_t)node * 256 + col] = f2bf(v);
                }
            }
        }
    }
}

__global__ __launch_bounds__(256, 1) void k_gemm2(const unsigned short* A, const unsigned short* wb,
                                                  const float* b2, unsigned short* g, float* out) {
    __shared__ unsigned short Bs[256 * 256];   // 128 KB
    int t = threadIdx.x;
    {
        const short8* src = (const short8*)wb;
        short8* dst = (short8*)Bs;
#pragma unroll
        for (int i = 0; i < 32; i++) dst[i * 256 + t] = src[i * 256 + t];
    }
    __syncthreads();
    int wv = t >> 6, lane = t & 63;
    int mrow = lane & 15, quad = lane >> 4;
    float bias[8];
#pragma unroll
    for (int i = 0; i < 8; i++) bias[i] = b2[i * 16 + mrow];
    for (int chunk = blockIdx.x; chunk < NCHUNK; chunk += gridDim.x) {
        int base = chunk * 128 + wv * 32;
        if (base >= NN) continue;
        short8 afr[2][8];
#pragma unroll
        for (int kk = 0; kk < 8; kk++) {
            afr[0][kk] = *(const short8*)(A + (size_t)(base + mrow) * 256 + kk * 32 + quad * 8);
            afr[1][kk] = *(const short8*)(A + (size_t)(base + 16 + mrow) * 256 + kk * 32 + quad * 8);
        }
        float4v acc[2][16];
#pragma unroll
        for (int h = 0; h < 2; h++)
#pragma unroll
            for (int ct = 0; ct < 16; ct++) acc[h][ct] = (float4v)(0.0f);
#pragma unroll
        for (int kk = 0; kk < 8; kk++) {
            int koff = kk * 32 + quad * 8;
#pragma unroll
            for (int ct = 0; ct < 16; ct++) {
                short8 b = *(const short8*)(Bs + (ct * 16 + mrow) * 256 + koff);
                acc[0][ct] = __builtin_amdgcn_mfma_f32_16x16x32_bf16(afr[0][kk], b, acc[0][ct], 0, 0, 0);
                acc[1][ct] = __builtin_amdgcn_mfma_f32_16x16x32_bf16(afr[1][kk], b, acc[1][ct], 0, 0, 0);
            }
        }
#pragma unroll
        for (int ct = 0; ct < 16; ct++) {
            int col = ct * 16 + mrow;
#pragma unroll
            for (int h = 0; h < 2; h++) {
#pragma unroll
                for (int r = 0; r < 4; r++) {
                    int node = base + h * 16 + quad * 4 + r;
                    float v = acc[h][ct][r];
                    if (ct < 8) {
                        g[(size_t)node * 128 + col] = f2bf(v);
                    } else {
                        out[(size_t)node * 128 + (col - 128)] = v + bias[ct - 8];
                    }
                }
            }
        }
    }
}

extern "C" void kernel_launch(void* const* d_in, const int* in_sizes, int n_in,
                              void* d_out, int out_size, void* d_ws, size_t ws_size,
                              hipStream_t stream) {
    const float* x   = (const float*)d_in[0];
    const int*   ei  = (const int*)d_in[1];
    const float* W1l = (const float*)d_in[2];
    const float* b1  = (const float*)d_in[3];
    const float* W1r = (const float*)d_in[4];
    const float* W2l = (const float*)d_in[5];
    const float* b2  = (const float*)d_in[6];
    const float* W2r = (const float*)d_in[7];
    float* out = (float*)d_out;

    char* p = (char*)d_ws;
    unsigned int* axb = (unsigned int*)p; p += (size_t)NN * 256 * 2;  // [agg(128) | x(128)] bf16
    unsigned short* h = (unsigned short*)p; p += (size_t)NN * 256 * 2;
    unsigned int* g   = (unsigned int*)p;  p += (size_t)NN * 128 * 2;
    unsigned short* wb1 = (unsigned short*)p; p += 65536 * 2;
    unsigned short* wb2 = (unsigned short*)p; p += 65536 * 2;
    int* deg  = (int*)p; p += (size_t)NN * 4;
    int* off  = (int*)p; p += (size_t)NN * 4;
    int* csr  = (int*)p; p += (size_t)NE * 4;
    int* bcnt = (int*)p; p += NB * 4;
    int* boff = (int*)p; p += (NB + 1) * 4;
    int* bcur = (int*)p; p += NB * 4;
    if (ws_size < (size_t)(p - (char*)d_ws)) return;
    uint2* pairs = (uint2*)h;   // overlay: pairs dead before gemm1 writes h

    hipMemsetAsync(bcnt, 0, NB * 4, stream);
    k_wconv<<<128, 256, 0, stream>>>(W1l, W1r, W2l, W2r, wb1, wb2);
    k_xconv<<<NN * 64 / 256, 256, 0, stream>>>(x, axb);
    k_bcount<<<256, 256, 0, stream>>>(ei, bcnt);
    k_bscan<<<1, NB, 0, stream>>>(bcnt, boff, bcur);
    k_bscatter<<<NCH, 256, 0, stream>>>(ei, bcur, pairs);
    k_build<<<NB, 256, 0, stream>>>(pairs, boff, off, deg, csr);
    k_agg1<<<NN * 64 / 256, 256, 0, stream>>>(axb, off, deg, csr, axb);
    k_gemm1<<<256, 256, 0, stream>>>((const unsigned short*)axb, wb1, b1, h);
    k_gemm2<<<256, 256, 0, stream>>>(h, wb2, b2, (unsigned short*)g, out);
    k_agg2<<<25000, 256, 0, stream>>>(g, off, deg, csr, out);
}